// Round 2
// baseline (180.057 us; speedup 1.0000x reference)
//
#include <hip/hip_runtime.h>
#include <hip/hip_bf16.h>
#include <math.h>

#define NF     16      // num features (K of low-rank projection)
#define INF    1024    // in_f
#define NPROTO 4096
#define NROWS  16384
#define OTILE  1024    // output cols per block in main_mm (4 per thread)
#define NTILE  128     // output rows per block in main_mm

// round f32 -> bf16 (RNE) and return as f32 value
__device__ __forceinline__ float bf16_rne(float x) {
    unsigned u = __float_as_uint(x);
    unsigned r = (u + 0x7FFFu + ((u >> 16) & 1u)) & 0xFFFF0000u;
    return __uint_as_float(r);
}

__device__ __forceinline__ float sigmoid5(float z) {
    return 1.0f / (1.0f + __expf(-5.0f * z));
}

// Butterfly transpose-reduce: v[64] per lane; afterwards lane L holds
// (sum over all 64 lanes of original v[L]) in v[0]. 63 shfl + 63 add.
__device__ __forceinline__ void xreduce64(float* v, int lane) {
#pragma unroll
    for (int s = 32; s >= 1; s >>= 1) {
        bool up = (lane & s) != 0;
#pragma unroll
        for (int j = 0; j < s; ++j) {
            float send = up ? v[j] : v[j + s];
            float recv = __shfl_xor(send, s, 64);
            v[j] = (up ? v[j + s] : v[j]) + recv;
        }
    }
}

// ---------------- Kernel A: build Pe[4096][32] ----------------
// Pe[o][k]    = |theta|*p_a[o][k] - |alpha|*(1 - p_s[o][k])
// Pe[o][16+k] = -|beta|*p_a[o][k]
__global__ __launch_bounds__(256) void build_pe(
    const float* __restrict__ proto, const float* __restrict__ feat,
    const float* __restrict__ theta, const float* __restrict__ alpha,
    const float* __restrict__ beta,  float* __restrict__ Pe)
{
    const int lane  = threadIdx.x & 63;
    const int wid   = threadIdx.x >> 6;
    const int rbase = blockIdx.x * 16 + wid * 4;   // 4 rows per wave
    const int i0    = lane * 16;

    const float th = fabsf(theta[0]);
    const float al = fabsf(alpha[0]);
    const float be = fabsf(beta[0]);

    float q[4][16];
#pragma unroll
    for (int r = 0; r < 4; ++r) {
        const float* wrow = proto + (size_t)(rbase + r) * INF + i0;
        float wb[16];
        float asum = 0.f;
#pragma unroll
        for (int j = 0; j < 16; j += 4) {
            float4 w4 = *(const float4*)(wrow + j);
            wb[j+0] = bf16_rne(w4.x); wb[j+1] = bf16_rne(w4.y);
            wb[j+2] = bf16_rne(w4.z); wb[j+3] = bf16_rne(w4.w);
            asum += fabsf(wb[j+0]) + fabsf(wb[j+1])
                  + fabsf(wb[j+2]) + fabsf(wb[j+3]);
        }
        // group of 64 elems = this lane quad (i0 = lane*16)
        asum += __shfl_xor(asum, 1, 64);
        asum += __shfl_xor(asum, 2, 64);
        float scale = bf16_rne(asum * (1.0f / 64.0f));
        scale = fmaxf(scale, 1e-8f);
        float inv = 1.0f / scale;
#pragma unroll
        for (int j = 0; j < 16; ++j) {
            float t = rintf(bf16_rne(wb[j] * inv));   // jnp.round = half-even
            t = fminf(fmaxf(t, -1.f), 1.f);
            q[r][j] = t * scale;                      // exact in bf16 set
        }
    }

    float acc[64];
#pragma unroll
    for (int i = 0; i < 64; ++i) acc[i] = 0.f;
#pragma unroll
    for (int k = 0; k < NF; ++k) {
        const float* frow = feat + k * INF + i0;
#pragma unroll
        for (int j = 0; j < 16; j += 4) {
            float4 f4 = *(const float4*)(frow + j);
#pragma unroll
            for (int r = 0; r < 4; ++r) {
                acc[r*16+k] = fmaf(q[r][j+0], f4.x, acc[r*16+k]);
                acc[r*16+k] = fmaf(q[r][j+1], f4.y, acc[r*16+k]);
                acc[r*16+k] = fmaf(q[r][j+2], f4.z, acc[r*16+k]);
                acc[r*16+k] = fmaf(q[r][j+3], f4.w, acc[r*16+k]);
            }
        }
    }
    xreduce64(acc, lane);
    // lane holds p_f for (r,k) = (lane>>4, lane&15)
    float pf = acc[0];
    float ps = sigmoid5(pf);
    float pa = pf * ps;
    int row = rbase + (lane >> 4);
    int k   = lane & 15;
    Pe[row * 32 + k]      = th * pa - al * (1.0f - ps);
    Pe[row * 32 + 16 + k] = -be * pa;
}

// ---------------- Kernel B: build Xe[16384][32] ----------------
// Xe[n][k] = x_a[n][k],  Xe[n][16+k] = 1 - x_s[n][k]
__global__ __launch_bounds__(256) void build_xe(
    const float* __restrict__ x, const float* __restrict__ feat,
    float* __restrict__ Xe)
{
    const int lane  = threadIdx.x & 63;
    const int wid   = threadIdx.x >> 6;
    const int rbase = blockIdx.x * 16 + wid * 4;
    const int i0    = lane * 16;

    float4 xv[4][4];
#pragma unroll
    for (int r = 0; r < 4; ++r) {
        const float* xrow = x + (size_t)(rbase + r) * INF + i0;
#pragma unroll
        for (int j = 0; j < 4; ++j) xv[r][j] = *(const float4*)(xrow + j * 4);
    }

    float acc[64];
#pragma unroll
    for (int i = 0; i < 64; ++i) acc[i] = 0.f;
#pragma unroll
    for (int k = 0; k < NF; ++k) {
        const float* frow = feat + k * INF + i0;
#pragma unroll
        for (int j = 0; j < 4; ++j) {
            float4 f4 = *(const float4*)(frow + j * 4);
#pragma unroll
            for (int r = 0; r < 4; ++r) {
                acc[r*16+k] = fmaf(xv[r][j].x, f4.x, acc[r*16+k]);
                acc[r*16+k] = fmaf(xv[r][j].y, f4.y, acc[r*16+k]);
                acc[r*16+k] = fmaf(xv[r][j].z, f4.z, acc[r*16+k]);
                acc[r*16+k] = fmaf(xv[r][j].w, f4.w, acc[r*16+k]);
            }
        }
    }
    xreduce64(acc, lane);
    float xf = acc[0];
    float xs = sigmoid5(xf);
    int row = rbase + (lane >> 4);
    int k   = lane & 15;
    Xe[row * 32 + k]      = xf * xs;
    Xe[row * 32 + 16 + k] = 1.0f - xs;
}

// ---------------- Kernel C: out = Xe (16384x32) @ Pe^T (4096x32) --------
// Thread owns 4 adjacent o columns (Pe rows in 128 VGPRs); Xe rows broadcast
// from LDS (same-address reads, conflict-free); coalesced float4 stores.
// Per row-iter: 8 ds_read_b128 (~96 LDS cyc) vs 128 v_fmac (256 VALU cyc)
// -> VALU-bound; 2 blocks/CU overlap LDS with VALU.
__global__ __launch_bounds__(256) void main_mm(
    const float* __restrict__ Xe, const float* __restrict__ Pe,
    float* __restrict__ out)
{
    __shared__ float4 xs4[NTILE * 8];   // 128 rows x 32 floats = 16 KiB
    const int t     = threadIdx.x;
    const int obase = blockIdx.x * OTILE;
    const int nbase = blockIdx.y * NTILE;

    // 4 Pe rows (output cols) per thread, kept in registers
    const float* p0 = Pe + (size_t)(obase + 4 * t) * 32;
    float4 P[4][8];
#pragma unroll
    for (int c = 0; c < 4; ++c)
#pragma unroll
        for (int j = 0; j < 8; ++j)
            P[c][j] = *(const float4*)(p0 + 32 * c + 4 * j);

    // stage Xe tile (128 rows x 32 f32)
    const float4* xsrc = (const float4*)(Xe + (size_t)nbase * 32);
#pragma unroll
    for (int j = 0; j < 4; ++j) xs4[t + 256 * j] = xsrc[t + 256 * j];
    __syncthreads();

    const float* xsf = (const float*)xs4;
    for (int n = 0; n < NTILE; ++n) {
        const float* xr = xsf + n * 32;
        float4 xq[8];
#pragma unroll
        for (int j = 0; j < 8; ++j) xq[j] = *(const float4*)(xr + 4 * j);
        float a[4];
#pragma unroll
        for (int c = 0; c < 4; ++c) {
            float s = 0.f;
#pragma unroll
            for (int j = 0; j < 8; ++j) {
                s = fmaf(xq[j].x, P[c][j].x, s);
                s = fmaf(xq[j].y, P[c][j].y, s);
                s = fmaf(xq[j].z, P[c][j].z, s);
                s = fmaf(xq[j].w, P[c][j].w, s);
            }
            a[c] = s;
        }
        *(float4*)(out + (size_t)(nbase + n) * NPROTO + obase + 4 * t)
            = make_float4(a[0], a[1], a[2], a[3]);
    }
}

extern "C" void kernel_launch(void* const* d_in, const int* in_sizes, int n_in,
                              void* d_out, int out_size, void* d_ws, size_t ws_size,
                              hipStream_t stream) {
    const float* x     = (const float*)d_in[0];
    const float* feat  = (const float*)d_in[1];
    const float* proto = (const float*)d_in[2];
    const float* theta = (const float*)d_in[3];
    const float* alpha = (const float*)d_in[4];
    const float* beta  = (const float*)d_in[5];
    float* out = (float*)d_out;

    float* Pe = (float*)d_ws;             // 4096*32*4  = 512 KiB
    float* Xe = Pe + (size_t)NPROTO * 32; // 16384*32*4 = 2 MiB

    build_pe<<<dim3(NPROTO / 16), 256, 0, stream>>>(proto, feat, theta, alpha, beta, Pe);
    build_xe<<<dim3(NROWS / 16), 256, 0, stream>>>(x, feat, Xe);
    main_mm<<<dim3(NPROTO / OTILE, NROWS / NTILE), 256, 0, stream>>>(Xe, Pe, out);
}

// Round 3
// 141.482 us; speedup vs baseline: 1.2727x; 1.2727x over previous
//
#include <hip/hip_runtime.h>
#include <hip/hip_bf16.h>
#include <math.h>

#define NF     16      // num features (K of low-rank projection)
#define INF    1024    // in_f
#define NPROTO 4096
#define NROWS  16384

typedef __attribute__((ext_vector_type(8))) short short8;   // 8 bf16 (4 VGPRs)
typedef __attribute__((ext_vector_type(4))) float f32x4;

// round f32 -> bf16 (RNE) and return as f32 value
__device__ __forceinline__ float bf16_rne(float x) {
    unsigned u = __float_as_uint(x);
    unsigned r = (u + 0x7FFFu + ((u >> 16) & 1u)) & 0xFFFF0000u;
    return __uint_as_float(r);
}

// split f32 v into bf16 hi + bf16 lo (v ~= hi + lo, err ~2^-17 rel)
__device__ __forceinline__ void split_bf16(float v, unsigned short& hi, unsigned short& lo) {
    unsigned u  = __float_as_uint(v);
    unsigned r  = u + 0x7FFFu + ((u >> 16) & 1u);
    hi = (unsigned short)(r >> 16);
    float hf = __uint_as_float(r & 0xFFFF0000u);
    float rem = v - hf;
    unsigned u2 = __float_as_uint(rem);
    unsigned r2 = u2 + 0x7FFFu + ((u2 >> 16) & 1u);
    lo = (unsigned short)(r2 >> 16);
}

__device__ __forceinline__ float sigmoid5(float z) {
    return 1.0f / (1.0f + __expf(-5.0f * z));
}

// Butterfly transpose-reduce: v[64] per lane; afterwards lane L holds
// (sum over all 64 lanes of original v[L]) in v[0]. 63 shfl + 63 add.
__device__ __forceinline__ void xreduce64(float* v, int lane) {
#pragma unroll
    for (int s = 32; s >= 1; s >>= 1) {
        bool up = (lane & s) != 0;
#pragma unroll
        for (int j = 0; j < s; ++j) {
            float send = up ? v[j] : v[j + s];
            float recv = __shfl_xor(send, s, 64);
            v[j] = (up ? v[j + s] : v[j]) + recv;
        }
    }
}

// ---------------- Kernel A: build Pe[4096][32] as bf16 hi/lo ----------------
// Pe[o][k]    = |theta|*p_a[o][k] - |alpha|*(1 - p_s[o][k])
// Pe[o][16+k] = -|beta|*p_a[o][k]
__global__ __launch_bounds__(256) void build_pe(
    const float* __restrict__ proto, const float* __restrict__ feat,
    const float* __restrict__ theta, const float* __restrict__ alpha,
    const float* __restrict__ beta,
    unsigned short* __restrict__ Ph, unsigned short* __restrict__ Pl)
{
    const int lane  = threadIdx.x & 63;
    const int wid   = threadIdx.x >> 6;
    const int rbase = blockIdx.x * 16 + wid * 4;   // 4 rows per wave
    const int i0    = lane * 16;

    const float th = fabsf(theta[0]);
    const float al = fabsf(alpha[0]);
    const float be = fabsf(beta[0]);

    float q[4][16];
#pragma unroll
    for (int r = 0; r < 4; ++r) {
        const float* wrow = proto + (size_t)(rbase + r) * INF + i0;
        float wb[16];
        float asum = 0.f;
#pragma unroll
        for (int j = 0; j < 16; j += 4) {
            float4 w4 = *(const float4*)(wrow + j);
            wb[j+0] = bf16_rne(w4.x); wb[j+1] = bf16_rne(w4.y);
            wb[j+2] = bf16_rne(w4.z); wb[j+3] = bf16_rne(w4.w);
            asum += fabsf(wb[j+0]) + fabsf(wb[j+1])
                  + fabsf(wb[j+2]) + fabsf(wb[j+3]);
        }
        // group of 64 elems = this lane quad (i0 = lane*16)
        asum += __shfl_xor(asum, 1, 64);
        asum += __shfl_xor(asum, 2, 64);
        float scale = bf16_rne(asum * (1.0f / 64.0f));
        scale = fmaxf(scale, 1e-8f);
        float inv = 1.0f / scale;
#pragma unroll
        for (int j = 0; j < 16; ++j) {
            float t = rintf(bf16_rne(wb[j] * inv));   // jnp.round = half-even
            t = fminf(fmaxf(t, -1.f), 1.f);
            q[r][j] = t * scale;                      // exact in bf16 set
        }
    }

    float acc[64];
#pragma unroll
    for (int i = 0; i < 64; ++i) acc[i] = 0.f;
#pragma unroll
    for (int k = 0; k < NF; ++k) {
        const float* frow = feat + k * INF + i0;
#pragma unroll
        for (int j = 0; j < 16; j += 4) {
            float4 f4 = *(const float4*)(frow + j);
#pragma unroll
            for (int r = 0; r < 4; ++r) {
                acc[r*16+k] = fmaf(q[r][j+0], f4.x, acc[r*16+k]);
                acc[r*16+k] = fmaf(q[r][j+1], f4.y, acc[r*16+k]);
                acc[r*16+k] = fmaf(q[r][j+2], f4.z, acc[r*16+k]);
                acc[r*16+k] = fmaf(q[r][j+3], f4.w, acc[r*16+k]);
            }
        }
    }
    xreduce64(acc, lane);
    // lane holds p_f for (r,k) = (lane>>4, lane&15)
    float pf = acc[0];
    float ps = sigmoid5(pf);
    float pa = pf * ps;
    int row = rbase + (lane >> 4);
    int k   = lane & 15;
    unsigned short h0, l0, h1, l1;
    split_bf16(th * pa - al * (1.0f - ps), h0, l0);
    split_bf16(-be * pa, h1, l1);
    Ph[row * 32 + k]      = h0;  Pl[row * 32 + k]      = l0;
    Ph[row * 32 + 16 + k] = h1;  Pl[row * 32 + 16 + k] = l1;
}

// ---------------- Kernel B: build Xe[16384][32] as bf16 hi/lo ----------------
// Xe[n][k] = x_a[n][k],  Xe[n][16+k] = 1 - x_s[n][k]
__global__ __launch_bounds__(256) void build_xe(
    const float* __restrict__ x, const float* __restrict__ feat,
    unsigned short* __restrict__ Xh, unsigned short* __restrict__ Xl)
{
    const int lane  = threadIdx.x & 63;
    const int wid   = threadIdx.x >> 6;
    const int rbase = blockIdx.x * 16 + wid * 4;
    const int i0    = lane * 16;

    float4 xv[4][4];
#pragma unroll
    for (int r = 0; r < 4; ++r) {
        const float* xrow = x + (size_t)(rbase + r) * INF + i0;
#pragma unroll
        for (int j = 0; j < 4; ++j) xv[r][j] = *(const float4*)(xrow + j * 4);
    }

    float acc[64];
#pragma unroll
    for (int i = 0; i < 64; ++i) acc[i] = 0.f;
#pragma unroll
    for (int k = 0; k < NF; ++k) {
        const float* frow = feat + k * INF + i0;
#pragma unroll
        for (int j = 0; j < 4; ++j) {
            float4 f4 = *(const float4*)(frow + j * 4);
#pragma unroll
            for (int r = 0; r < 4; ++r) {
                acc[r*16+k] = fmaf(xv[r][j].x, f4.x, acc[r*16+k]);
                acc[r*16+k] = fmaf(xv[r][j].y, f4.y, acc[r*16+k]);
                acc[r*16+k] = fmaf(xv[r][j].z, f4.z, acc[r*16+k]);
                acc[r*16+k] = fmaf(xv[r][j].w, f4.w, acc[r*16+k]);
            }
        }
    }
    xreduce64(acc, lane);
    float xf = acc[0];
    float xs = sigmoid5(xf);
    int row = rbase + (lane >> 4);
    int k   = lane & 15;
    unsigned short h0, l0, h1, l1;
    split_bf16(xf * xs, h0, l0);
    split_bf16(1.0f - xs, h1, l1);
    Xh[row * 32 + k]      = h0;  Xl[row * 32 + k]      = l0;
    Xh[row * 32 + 16 + k] = h1;  Xl[row * 32 + 16 + k] = l1;
}

// ------- Kernel C: out = Xe (16384x32) @ Pe^T (4096x32), MFMA hi/lo -------
// Block = 4 waves, 64 rows x 64 cols. Wave w: rows [nbase, nbase+16).
// Fragments load straight from global (L2-resident, 2.5 MB total).
// A-frag: lane(m=lane&15, b=lane>>4) reads Xh[(nbase+m)*32 + b*8 .. +7]
// B-frag: lane reads Ph[(obase+m)*32 + b*8 .. +7]   (Pe stored [o][k] = B^T)
// C: col = lane&15, row = b*4 + r  (m89-verified layout)
__global__ __launch_bounds__(256) void main_mm_mfma(
    const unsigned short* __restrict__ Xh, const unsigned short* __restrict__ Xl,
    const unsigned short* __restrict__ Ph, const unsigned short* __restrict__ Pl,
    float* __restrict__ out)
{
    const int lane   = threadIdx.x & 63;
    const int w      = threadIdx.x >> 6;
    const int m      = lane & 15;
    const int b      = lane >> 4;
    const int nbase  = blockIdx.y * 64 + w * 16;
    const int obase0 = blockIdx.x * 64;

    const size_t aoff = (size_t)(nbase + m) * 32 + b * 8;
    const short8 Ah = *(const short8*)(Xh + aoff);
    const short8 Al = *(const short8*)(Xl + aoff);

#pragma unroll
    for (int c = 0; c < 4; ++c) {
        const int obase = obase0 + c * 16;
        const size_t boff = (size_t)(obase + m) * 32 + b * 8;
        const short8 Bh = *(const short8*)(Ph + boff);
        const short8 Bl = *(const short8*)(Pl + boff);
        f32x4 acc = {0.f, 0.f, 0.f, 0.f};
        acc = __builtin_amdgcn_mfma_f32_16x16x32_bf16(Ah, Bh, acc, 0, 0, 0);
        acc = __builtin_amdgcn_mfma_f32_16x16x32_bf16(Ah, Bl, acc, 0, 0, 0);
        acc = __builtin_amdgcn_mfma_f32_16x16x32_bf16(Al, Bh, acc, 0, 0, 0);
        acc = __builtin_amdgcn_mfma_f32_16x16x32_bf16(Al, Bl, acc, 0, 0, 0);
        float* orow = out + (size_t)(nbase + b * 4) * NPROTO + obase + m;
#pragma unroll
        for (int r = 0; r < 4; ++r) orow[(size_t)r * NPROTO] = acc[r];
    }
}

extern "C" void kernel_launch(void* const* d_in, const int* in_sizes, int n_in,
                              void* d_out, int out_size, void* d_ws, size_t ws_size,
                              hipStream_t stream) {
    const float* x     = (const float*)d_in[0];
    const float* feat  = (const float*)d_in[1];
    const float* proto = (const float*)d_in[2];
    const float* theta = (const float*)d_in[3];
    const float* alpha = (const float*)d_in[4];
    const float* beta  = (const float*)d_in[5];
    float* out = (float*)d_out;

    unsigned short* Ph = (unsigned short*)d_ws;          // 256 KiB
    unsigned short* Pl = Ph + (size_t)NPROTO * 32;       // 256 KiB
    unsigned short* Xh = Pl + (size_t)NPROTO * 32;       // 1 MiB
    unsigned short* Xl = Xh + (size_t)NROWS * 32;        // 1 MiB

    build_pe<<<dim3(NPROTO / 16), 256, 0, stream>>>(proto, feat, theta, alpha, beta, Ph, Pl);
    build_xe<<<dim3(NROWS / 16), 256, 0, stream>>>(x, feat, Xh, Xl);
    main_mm_mfma<<<dim3(NPROTO / 64, NROWS / 64), 256, 0, stream>>>(Xh, Xl, Ph, Pl, out);
}

// Round 5
// 131.241 us; speedup vs baseline: 1.3720x; 1.0780x over previous
//
#include <hip/hip_runtime.h>
#include <hip/hip_bf16.h>
#include <math.h>

#define NF     16      // num features (K of low-rank projection)
#define INF    1024    // in_f
#define NPROTO 4096
#define NROWS  16384

typedef __attribute__((ext_vector_type(8))) short short8;   // 8 bf16 (4 VGPRs)
typedef __attribute__((ext_vector_type(4))) float f32x4;

// round f32 -> bf16 (RNE) and return as f32 value
__device__ __forceinline__ float bf16_rne(float x) {
    unsigned u = __float_as_uint(x);
    unsigned r = (u + 0x7FFFu + ((u >> 16) & 1u)) & 0xFFFF0000u;
    return __uint_as_float(r);
}

// split f32 v into bf16 hi + bf16 lo (v ~= hi + lo, err ~2^-17 rel)
__device__ __forceinline__ void split_bf16(float v, unsigned short& hi, unsigned short& lo) {
    unsigned u  = __float_as_uint(v);
    unsigned r  = u + 0x7FFFu + ((u >> 16) & 1u);
    hi = (unsigned short)(r >> 16);
    float hf = __uint_as_float(r & 0xFFFF0000u);
    float rem = v - hf;
    unsigned u2 = __float_as_uint(rem);
    unsigned r2 = u2 + 0x7FFFu + ((u2 >> 16) & 1u);
    lo = (unsigned short)(r2 >> 16);
}

__device__ __forceinline__ float sigmoid5(float z) {
    return 1.0f / (1.0f + __expf(-5.0f * z));
}

// Butterfly transpose-reduce: v[64] per lane; afterwards lane L holds
// (sum over all 64 lanes of original v[L]) in v[0]. 63 shfl + 63 add.
__device__ __forceinline__ void xreduce64(float* v, int lane) {
#pragma unroll
    for (int s = 32; s >= 1; s >>= 1) {
        bool up = (lane & s) != 0;
#pragma unroll
        for (int j = 0; j < s; ++j) {
            float send = up ? v[j] : v[j + s];
            float recv = __shfl_xor(send, s, 64);
            v[j] = (up ? v[j + s] : v[j]) + recv;
        }
    }
}

// ---------------- prep part A: Pe rows -> bf16 hi/lo ----------------
// Pe[o][k]    = |theta|*p_a[o][k] - |alpha|*(1 - p_s[o][k])
// Pe[o][16+k] = -|beta|*p_a[o][k]
__device__ __forceinline__ void do_build_pe(
    int blk,
    const float* __restrict__ proto, const float* __restrict__ feat,
    const float* __restrict__ theta, const float* __restrict__ alpha,
    const float* __restrict__ beta,
    unsigned short* __restrict__ Ph, unsigned short* __restrict__ Pl)
{
    const int lane  = threadIdx.x & 63;
    const int wid   = threadIdx.x >> 6;
    const int rbase = blk * 16 + wid * 4;   // 4 rows per wave
    const int i0    = lane * 16;

    const float th = fabsf(theta[0]);
    const float al = fabsf(alpha[0]);
    const float be = fabsf(beta[0]);

    float q[4][16];
#pragma unroll
    for (int r = 0; r < 4; ++r) {
        const float* wrow = proto + (size_t)(rbase + r) * INF + i0;
        float wb[16];
        float asum = 0.f;
#pragma unroll
        for (int j = 0; j < 16; j += 4) {
            float4 w4 = *(const float4*)(wrow + j);
            wb[j+0] = bf16_rne(w4.x); wb[j+1] = bf16_rne(w4.y);
            wb[j+2] = bf16_rne(w4.z); wb[j+3] = bf16_rne(w4.w);
            asum += fabsf(wb[j+0]) + fabsf(wb[j+1])
                  + fabsf(wb[j+2]) + fabsf(wb[j+3]);
        }
        // group of 64 elems = this lane quad (i0 = lane*16)
        asum += __shfl_xor(asum, 1, 64);
        asum += __shfl_xor(asum, 2, 64);
        float scale = bf16_rne(asum * (1.0f / 64.0f));
        scale = fmaxf(scale, 1e-8f);
        float inv = 1.0f / scale;
#pragma unroll
        for (int j = 0; j < 16; ++j) {
            float t = rintf(bf16_rne(wb[j] * inv));   // jnp.round = half-even
            t = fminf(fmaxf(t, -1.f), 1.f);
            q[r][j] = t * scale;                      // exact in bf16 set
        }
    }

    float acc[64];
#pragma unroll
    for (int i = 0; i < 64; ++i) acc[i] = 0.f;
#pragma unroll
    for (int k = 0; k < NF; ++k) {
        const float* frow = feat + k * INF + i0;
#pragma unroll
        for (int j = 0; j < 16; j += 4) {
            float4 f4 = *(const float4*)(frow + j);
#pragma unroll
            for (int r = 0; r < 4; ++r) {
                acc[r*16+k] = fmaf(q[r][j+0], f4.x, acc[r*16+k]);
                acc[r*16+k] = fmaf(q[r][j+1], f4.y, acc[r*16+k]);
                acc[r*16+k] = fmaf(q[r][j+2], f4.z, acc[r*16+k]);
                acc[r*16+k] = fmaf(q[r][j+3], f4.w, acc[r*16+k]);
            }
        }
    }
    xreduce64(acc, lane);
    // lane holds p_f for (r,k) = (lane>>4, lane&15)
    float pf = acc[0];
    float ps = sigmoid5(pf);
    float pa = pf * ps;
    int row = rbase + (lane >> 4);
    int k   = lane & 15;
    unsigned short h0, l0, h1, l1;
    split_bf16(th * pa - al * (1.0f - ps), h0, l0);
    split_bf16(-be * pa, h1, l1);
    Ph[row * 32 + k]      = h0;  Pl[row * 32 + k]      = l0;
    Ph[row * 32 + 16 + k] = h1;  Pl[row * 32 + 16 + k] = l1;
}

// ---------------- prep part B: Xe rows -> bf16 hi/lo ----------------
// Xe[n][k] = x_a[n][k],  Xe[n][16+k] = 1 - x_s[n][k]
__device__ __forceinline__ void do_build_xe(
    int blk,
    const float* __restrict__ x, const float* __restrict__ feat,
    unsigned short* __restrict__ Xh, unsigned short* __restrict__ Xl)
{
    const int lane  = threadIdx.x & 63;
    const int wid   = threadIdx.x >> 6;
    const int rbase = blk * 16 + wid * 4;
    const int i0    = lane * 16;

    float4 xv[4][4];
#pragma unroll
    for (int r = 0; r < 4; ++r) {
        const float* xrow = x + (size_t)(rbase + r) * INF + i0;
#pragma unroll
        for (int j = 0; j < 4; ++j) xv[r][j] = *(const float4*)(xrow + j * 4);
    }

    float acc[64];
#pragma unroll
    for (int i = 0; i < 64; ++i) acc[i] = 0.f;
#pragma unroll
    for (int k = 0; k < NF; ++k) {
        const float* frow = feat + k * INF + i0;
#pragma unroll
        for (int j = 0; j < 4; ++j) {
            float4 f4 = *(const float4*)(frow + j * 4);
#pragma unroll
            for (int r = 0; r < 4; ++r) {
                acc[r*16+k] = fmaf(xv[r][j].x, f4.x, acc[r*16+k]);
                acc[r*16+k] = fmaf(xv[r][j].y, f4.y, acc[r*16+k]);
                acc[r*16+k] = fmaf(xv[r][j].z, f4.z, acc[r*16+k]);
                acc[r*16+k] = fmaf(xv[r][j].w, f4.w, acc[r*16+k]);
            }
        }
    }
    xreduce64(acc, lane);
    float xf = acc[0];
    float xs = sigmoid5(xf);
    int row = rbase + (lane >> 4);
    int k   = lane & 15;
    unsigned short h0, l0, h1, l1;
    split_bf16(xf * xs, h0, l0);
    split_bf16(1.0f - xs, h1, l1);
    Xh[row * 32 + k]      = h0;  Xl[row * 32 + k]      = l0;
    Xh[row * 32 + 16 + k] = h1;  Xl[row * 32 + 16 + k] = l1;
}

// Fused prep: blocks [0,256) build Pe, blocks [256,1280) build Xe.
__global__ __launch_bounds__(256) void prep(
    const float* __restrict__ x, const float* __restrict__ feat,
    const float* __restrict__ proto,
    const float* __restrict__ theta, const float* __restrict__ alpha,
    const float* __restrict__ beta,
    unsigned short* __restrict__ Ph, unsigned short* __restrict__ Pl,
    unsigned short* __restrict__ Xh, unsigned short* __restrict__ Xl)
{
    const int blk = blockIdx.x;
    if (blk < NPROTO / 16) {
        do_build_pe(blk, proto, feat, theta, alpha, beta, Ph, Pl);
    } else {
        do_build_xe(blk - NPROTO / 16, x, feat, Xh, Xl);
    }
}

// ------- main: out = Xe (16384x32) @ Pe^T (4096x32), MFMA hi/lo -------
// Operands SWAPPED vs R3: A-slot = Pe (o = A-rows), B-slot = Xe (n = B-cols).
// C layout (m89): col = lane&15 -> n, row = (lane>>4)*4+reg -> o. The 4 acc
// regs are 4 CONSECUTIVE o columns of one n row -> one float4 (dwordx4)
// nontemporal store per tile: 64 lanes x 16 B = 1 KB/instr, no L2
// write-allocate on the streamed 268 MB output.
__global__ __launch_bounds__(256) void main_mm_mfma(
    const unsigned short* __restrict__ Xh, const unsigned short* __restrict__ Xl,
    const unsigned short* __restrict__ Ph, const unsigned short* __restrict__ Pl,
    float* __restrict__ out)
{
    const int lane   = threadIdx.x & 63;
    const int w      = threadIdx.x >> 6;
    const int m      = lane & 15;
    const int b      = lane >> 4;
    const int nbase  = blockIdx.y * 64 + w * 16;
    const int obase0 = blockIdx.x * 64;

    // B fragment (Xe): col = n, loaded once per wave
    const size_t boff = (size_t)(nbase + m) * 32 + b * 8;
    const short8 Bh = *(const short8*)(Xh + boff);
    const short8 Bl = *(const short8*)(Xl + boff);

#pragma unroll
    for (int c = 0; c < 4; ++c) {
        const int ob = obase0 + c * 16;
        const size_t aoff = (size_t)(ob + m) * 32 + b * 8;
        const short8 Ah = *(const short8*)(Ph + aoff);
        const short8 Al = *(const short8*)(Pl + aoff);
        f32x4 acc = {0.f, 0.f, 0.f, 0.f};
        acc = __builtin_amdgcn_mfma_f32_16x16x32_bf16(Ah, Bh, acc, 0, 0, 0);
        acc = __builtin_amdgcn_mfma_f32_16x16x32_bf16(Ah, Bl, acc, 0, 0, 0);
        acc = __builtin_amdgcn_mfma_f32_16x16x32_bf16(Al, Bh, acc, 0, 0, 0);
        acc = __builtin_amdgcn_mfma_f32_16x16x32_bf16(Al, Bl, acc, 0, 0, 0);
        f32x4* dst = (f32x4*)(out + (size_t)(nbase + m) * NPROTO + ob + b * 4);
        __builtin_nontemporal_store(acc, dst);
    }
}

extern "C" void kernel_launch(void* const* d_in, const int* in_sizes, int n_in,
                              void* d_out, int out_size, void* d_ws, size_t ws_size,
                              hipStream_t stream) {
    const float* x     = (const float*)d_in[0];
    const float* feat  = (const float*)d_in[1];
    const float* proto = (const float*)d_in[2];
    const float* theta = (const float*)d_in[3];
    const float* alpha = (const float*)d_in[4];
    const float* beta  = (const float*)d_in[5];
    float* out = (float*)d_out;

    unsigned short* Ph = (unsigned short*)d_ws;          // 256 KiB
    unsigned short* Pl = Ph + (size_t)NPROTO * 32;       // 256 KiB
    unsigned short* Xh = Pl + (size_t)NPROTO * 32;       // 1 MiB
    unsigned short* Xl = Xh + (size_t)NROWS * 32;        // 1 MiB

    prep<<<dim3(NPROTO / 16 + NROWS / 16), 256, 0, stream>>>(
        x, feat, proto, theta, alpha, beta, Ph, Pl, Xh, Xl);
    main_mm_mfma<<<dim3(NPROTO / 64, NROWS / 64), 256, 0, stream>>>(Xh, Xl, Ph, Pl, out);
}

// Round 7
// 124.436 us; speedup vs baseline: 1.4470x; 1.0547x over previous
//
#include <hip/hip_runtime.h>
#include <hip/hip_bf16.h>
#include <math.h>

#define NF     16      // num features (K of low-rank projection)
#define INF    1024    // in_f
#define NPROTO 4096
#define NROWS  16384

typedef __attribute__((ext_vector_type(8))) short short8;   // 8 bf16 (4 VGPRs)
typedef __attribute__((ext_vector_type(4))) float f32x4;

// round f32 -> bf16 (RNE) and return as f32 value
__device__ __forceinline__ float bf16_rne(float x) {
    unsigned u = __float_as_uint(x);
    unsigned r = (u + 0x7FFFu + ((u >> 16) & 1u)) & 0xFFFF0000u;
    return __uint_as_float(r);
}

// split f32 v into bf16 hi + bf16 lo (v ~= hi + lo, err ~2^-17 rel)
__device__ __forceinline__ void split_bf16(float v, unsigned short& hi, unsigned short& lo) {
    unsigned u  = __float_as_uint(v);
    unsigned r  = u + 0x7FFFu + ((u >> 16) & 1u);
    hi = (unsigned short)(r >> 16);
    float hf = __uint_as_float(r & 0xFFFF0000u);
    float rem = v - hf;
    unsigned u2 = __float_as_uint(rem);
    unsigned r2 = u2 + 0x7FFFu + ((u2 >> 16) & 1u);
    lo = (unsigned short)(r2 >> 16);
}

__device__ __forceinline__ float sigmoid5(float z) {
    return 1.0f / (1.0f + __expf(-5.0f * z));
}

// Butterfly transpose-reduce: v[64] per lane; afterwards lane L holds
// (sum over all 64 lanes of original v[L]) in v[0]. 63 shfl + 63 add.
__device__ __forceinline__ void xreduce64(float* v, int lane) {
#pragma unroll
    for (int s = 32; s >= 1; s >>= 1) {
        bool up = (lane & s) != 0;
#pragma unroll
        for (int j = 0; j < s; ++j) {
            float send = up ? v[j] : v[j + s];
            float recv = __shfl_xor(send, s, 64);
            v[j] = (up ? v[j + s] : v[j]) + recv;
        }
    }
}

// ---------------- prep part A: Pe rows -> bf16 hi/lo ----------------
// Pe[o][k]    = |theta|*p_a[o][k] - |alpha|*(1 - p_s[o][k])
// Pe[o][16+k] = -|beta|*p_a[o][k]
__device__ __forceinline__ void do_build_pe(
    int blk,
    const float* __restrict__ proto, const float* __restrict__ feat,
    const float* __restrict__ theta, const float* __restrict__ alpha,
    const float* __restrict__ beta,
    unsigned short* __restrict__ Ph, unsigned short* __restrict__ Pl)
{
    const int lane  = threadIdx.x & 63;
    const int wid   = threadIdx.x >> 6;
    const int rbase = blk * 16 + wid * 4;   // 4 rows per wave
    const int i0    = lane * 16;

    const float th = fabsf(theta[0]);
    const float al = fabsf(alpha[0]);
    const float be = fabsf(beta[0]);

    float q[4][16];
#pragma unroll
    for (int r = 0; r < 4; ++r) {
        const float* wrow = proto + (size_t)(rbase + r) * INF + i0;
        float wb[16];
        float asum = 0.f;
#pragma unroll
        for (int j = 0; j < 16; j += 4) {
            float4 w4 = *(const float4*)(wrow + j);
            wb[j+0] = bf16_rne(w4.x); wb[j+1] = bf16_rne(w4.y);
            wb[j+2] = bf16_rne(w4.z); wb[j+3] = bf16_rne(w4.w);
            asum += fabsf(wb[j+0]) + fabsf(wb[j+1])
                  + fabsf(wb[j+2]) + fabsf(wb[j+3]);
        }
        // group of 64 elems = this lane quad (i0 = lane*16)
        asum += __shfl_xor(asum, 1, 64);
        asum += __shfl_xor(asum, 2, 64);
        float scale = bf16_rne(asum * (1.0f / 64.0f));
        scale = fmaxf(scale, 1e-8f);
        float inv = 1.0f / scale;
#pragma unroll
        for (int j = 0; j < 16; ++j) {
            float t = rintf(bf16_rne(wb[j] * inv));   // jnp.round = half-even
            t = fminf(fmaxf(t, -1.f), 1.f);
            q[r][j] = t * scale;                      // exact in bf16 set
        }
    }

    float acc[64];
#pragma unroll
    for (int i = 0; i < 64; ++i) acc[i] = 0.f;
#pragma unroll
    for (int k = 0; k < NF; ++k) {
        const float* frow = feat + k * INF + i0;
#pragma unroll
        for (int j = 0; j < 16; j += 4) {
            float4 f4 = *(const float4*)(frow + j);
#pragma unroll
            for (int r = 0; r < 4; ++r) {
                acc[r*16+k] = fmaf(q[r][j+0], f4.x, acc[r*16+k]);
                acc[r*16+k] = fmaf(q[r][j+1], f4.y, acc[r*16+k]);
                acc[r*16+k] = fmaf(q[r][j+2], f4.z, acc[r*16+k]);
                acc[r*16+k] = fmaf(q[r][j+3], f4.w, acc[r*16+k]);
            }
        }
    }
    xreduce64(acc, lane);
    // lane holds p_f for (r,k) = (lane>>4, lane&15)
    float pf = acc[0];
    float ps = sigmoid5(pf);
    float pa = pf * ps;
    int row = rbase + (lane >> 4);
    int k   = lane & 15;
    unsigned short h0, l0, h1, l1;
    split_bf16(th * pa - al * (1.0f - ps), h0, l0);
    split_bf16(-be * pa, h1, l1);
    Ph[row * 32 + k]      = h0;  Pl[row * 32 + k]      = l0;
    Ph[row * 32 + 16 + k] = h1;  Pl[row * 32 + 16 + k] = l1;
}

// ---------------- prep part B: Xe rows -> bf16 hi/lo ----------------
// Xe[n][k] = x_a[n][k],  Xe[n][16+k] = 1 - x_s[n][k]
__device__ __forceinline__ void do_build_xe(
    int blk,
    const float* __restrict__ x, const float* __restrict__ feat,
    unsigned short* __restrict__ Xh, unsigned short* __restrict__ Xl)
{
    const int lane  = threadIdx.x & 63;
    const int wid   = threadIdx.x >> 6;
    const int rbase = blk * 16 + wid * 4;
    const int i0    = lane * 16;

    float4 xv[4][4];
#pragma unroll
    for (int r = 0; r < 4; ++r) {
        const float* xrow = x + (size_t)(rbase + r) * INF + i0;
#pragma unroll
        for (int j = 0; j < 4; ++j) xv[r][j] = *(const float4*)(xrow + j * 4);
    }

    float acc[64];
#pragma unroll
    for (int i = 0; i < 64; ++i) acc[i] = 0.f;
#pragma unroll
    for (int k = 0; k < NF; ++k) {
        const float* frow = feat + k * INF + i0;
#pragma unroll
        for (int j = 0; j < 4; ++j) {
            float4 f4 = *(const float4*)(frow + j * 4);
#pragma unroll
            for (int r = 0; r < 4; ++r) {
                acc[r*16+k] = fmaf(xv[r][j].x, f4.x, acc[r*16+k]);
                acc[r*16+k] = fmaf(xv[r][j].y, f4.y, acc[r*16+k]);
                acc[r*16+k] = fmaf(xv[r][j].z, f4.z, acc[r*16+k]);
                acc[r*16+k] = fmaf(xv[r][j].w, f4.w, acc[r*16+k]);
            }
        }
    }
    xreduce64(acc, lane);
    float xf = acc[0];
    float xs = sigmoid5(xf);
    int row = rbase + (lane >> 4);
    int k   = lane & 15;
    unsigned short h0, l0, h1, l1;
    split_bf16(xf * xs, h0, l0);
    split_bf16(1.0f - xs, h1, l1);
    Xh[row * 32 + k]      = h0;  Xl[row * 32 + k]      = l0;
    Xh[row * 32 + 16 + k] = h1;  Xl[row * 32 + 16 + k] = l1;
}

// Fused prep: blocks [0,256) build Pe, blocks [256,1280) build Xe.
__global__ __launch_bounds__(256) void prep(
    const float* __restrict__ x, const float* __restrict__ feat,
    const float* __restrict__ proto,
    const float* __restrict__ theta, const float* __restrict__ alpha,
    const float* __restrict__ beta,
    unsigned short* __restrict__ Ph, unsigned short* __restrict__ Pl,
    unsigned short* __restrict__ Xh, unsigned short* __restrict__ Xl)
{
    const int blk = blockIdx.x;
    if (blk < NPROTO / 16) {
        do_build_pe(blk, proto, feat, theta, alpha, beta, Ph, Pl);
    } else {
        do_build_xe(blk - NPROTO / 16, x, feat, Xh, Xl);
    }
}

// ------- main: out = Xe (16384x32) @ Pe^T (4096x32), MFMA hi/lo -------
// Wave computes a 16n x 256o tile (16 o-tiles, 64 MFMA), transposes it via
// wave-private XOR-swizzled LDS, then stores 16 rows as 1 KB-contiguous NT
// dwordx4 (64 lanes x 16 B in ONE row) — the fillBuffer-like store pattern.
// MFMA C layout (m89): col=lane&15 -> n, row=(lane>>4)*4+reg -> o.
__global__ __launch_bounds__(256) void main_mm_mfma(
    const unsigned short* __restrict__ Xh, const unsigned short* __restrict__ Xl,
    const unsigned short* __restrict__ Ph, const unsigned short* __restrict__ Pl,
    float* __restrict__ out)
{
    __shared__ float lds[4][16][256];   // 64 KiB: per-wave 16 rows x 256 cols
    const int lane  = threadIdx.x & 63;
    const int w     = threadIdx.x >> 6;
    const int m     = lane & 15;        // n within tile (C col)
    const int b     = lane >> 4;        // K-group / C row-group
    const int nbase = blockIdx.y * 64 + w * 16;
    const int ob    = blockIdx.x * 256;

    // B fragment (Xe): col = n, loaded once per wave
    const size_t boff = (size_t)(nbase + m) * 32 + b * 8;
    const short8 Bh = *(const short8*)(Xh + boff);
    const short8 Bl = *(const short8*)(Xl + boff);

    // col-XOR swizzle: logical col c of row r stored at c ^ (4*(r&7))
    const int wsw = 4 * (m & 7);
    float* myrow = &lds[w][m][0];
#pragma unroll
    for (int t = 0; t < 16; ++t) {
        const size_t aoff = (size_t)(ob + t * 16 + m) * 32 + b * 8;
        const short8 Ah = *(const short8*)(Ph + aoff);
        const short8 Al = *(const short8*)(Pl + aoff);
        f32x4 acc = {0.f, 0.f, 0.f, 0.f};
        acc = __builtin_amdgcn_mfma_f32_16x16x32_bf16(Ah, Bh, acc, 0, 0, 0);
        acc = __builtin_amdgcn_mfma_f32_16x16x32_bf16(Ah, Bl, acc, 0, 0, 0);
        acc = __builtin_amdgcn_mfma_f32_16x16x32_bf16(Al, Bh, acc, 0, 0, 0);
        acc = __builtin_amdgcn_mfma_f32_16x16x32_bf16(Al, Bl, acc, 0, 0, 0);
        *(f32x4*)(myrow + ((t * 16 + b * 4) ^ wsw)) = acc;  // 4-aligned XOR
    }
    __syncthreads();

    const float* src = &lds[w][0][0];
#pragma unroll
    for (int r = 0; r < 16; ++r) {
        f32x4 v = *(const f32x4*)(src + r * 256 + ((lane * 4) ^ (4 * (r & 7))));
        f32x4* dst = (f32x4*)(out + (size_t)(nbase + r) * NPROTO + ob + lane * 4);
        __builtin_nontemporal_store(v, dst);
    }
}

extern "C" void kernel_launch(void* const* d_in, const int* in_sizes, int n_in,
                              void* d_out, int out_size, void* d_ws, size_t ws_size,
                              hipStream_t stream) {
    const float* x     = (const float*)d_in[0];
    const float* feat  = (const float*)d_in[1];
    const float* proto = (const float*)d_in[2];
    const float* theta = (const float*)d_in[3];
    const float* alpha = (const float*)d_in[4];
    const float* beta  = (const float*)d_in[5];
    float* out = (float*)d_out;

    unsigned short* Ph = (unsigned short*)d_ws;          // 256 KiB
    unsigned short* Pl = Ph + (size_t)NPROTO * 32;       // 256 KiB
    unsigned short* Xh = Pl + (size_t)NPROTO * 32;       // 1 MiB
    unsigned short* Xl = Xh + (size_t)NROWS * 32;        // 1 MiB

    prep<<<dim3(NPROTO / 16 + NROWS / 16), 256, 0, stream>>>(
        x, feat, proto, theta, alpha, beta, Ph, Pl, Xh, Xl);
    main_mm_mfma<<<dim3(NPROTO / 256, NROWS / 64), 256, 0, stream>>>(Xh, Xl, Ph, Pl, out);
}

// Round 9
// 123.962 us; speedup vs baseline: 1.4525x; 1.0038x over previous
//
#include <hip/hip_runtime.h>
#include <hip/hip_bf16.h>
#include <math.h>

#define NF     16      // num features (K of low-rank projection)
#define INF    1024    // in_f
#define NPROTO 4096
#define NROWS  16384

typedef __attribute__((ext_vector_type(8))) short short8;   // 8 bf16 (4 VGPRs)
typedef __attribute__((ext_vector_type(4))) float f32x4;

// round f32 -> bf16 (RNE) and return as f32 value
__device__ __forceinline__ float bf16_rne(float x) {
    unsigned u = __float_as_uint(x);
    unsigned r = (u + 0x7FFFu + ((u >> 16) & 1u)) & 0xFFFF0000u;
    return __uint_as_float(r);
}

// split f32 v into bf16 hi + bf16 lo (v ~= hi + lo, err ~2^-17 rel)
__device__ __forceinline__ void split_bf16(float v, unsigned short& hi, unsigned short& lo) {
    unsigned u  = __float_as_uint(v);
    unsigned r  = u + 0x7FFFu + ((u >> 16) & 1u);
    hi = (unsigned short)(r >> 16);
    float hf = __uint_as_float(r & 0xFFFF0000u);
    float rem = v - hf;
    unsigned u2 = __float_as_uint(rem);
    unsigned r2 = u2 + 0x7FFFu + ((u2 >> 16) & 1u);
    lo = (unsigned short)(r2 >> 16);
}

__device__ __forceinline__ float sigmoid5(float z) {
    return 1.0f / (1.0f + __expf(-5.0f * z));
}

// Butterfly transpose-reduce: v[64] per lane; afterwards lane L holds
// (sum over all 64 lanes of original v[L]) in v[0]. 63 shfl + 63 add.
__device__ __forceinline__ void xreduce64(float* v, int lane) {
#pragma unroll
    for (int s = 32; s >= 1; s >>= 1) {
        bool up = (lane & s) != 0;
#pragma unroll
        for (int j = 0; j < s; ++j) {
            float send = up ? v[j] : v[j + s];
            float recv = __shfl_xor(send, s, 64);
            v[j] = (up ? v[j + s] : v[j]) + recv;
        }
    }
}

// ---------------- prep part A: Pe rows -> bf16 hi/lo ----------------
// Pe[o][k]    = |theta|*p_a[o][k] - |alpha|*(1 - p_s[o][k])
// Pe[o][16+k] = -|beta|*p_a[o][k]
__device__ __forceinline__ void do_build_pe(
    int blk,
    const float* __restrict__ proto, const float* __restrict__ feat,
    const float* __restrict__ theta, const float* __restrict__ alpha,
    const float* __restrict__ beta,
    unsigned short* __restrict__ Ph, unsigned short* __restrict__ Pl)
{
    const int lane  = threadIdx.x & 63;
    const int wid   = threadIdx.x >> 6;
    const int rbase = blk * 16 + wid * 4;   // 4 rows per wave
    const int i0    = lane * 16;

    const float th = fabsf(theta[0]);
    const float al = fabsf(alpha[0]);
    const float be = fabsf(beta[0]);

    float q[4][16];
#pragma unroll
    for (int r = 0; r < 4; ++r) {
        const float* wrow = proto + (size_t)(rbase + r) * INF + i0;
        float wb[16];
        float asum = 0.f;
#pragma unroll
        for (int j = 0; j < 16; j += 4) {
            float4 w4 = *(const float4*)(wrow + j);
            wb[j+0] = bf16_rne(w4.x); wb[j+1] = bf16_rne(w4.y);
            wb[j+2] = bf16_rne(w4.z); wb[j+3] = bf16_rne(w4.w);
            asum += fabsf(wb[j+0]) + fabsf(wb[j+1])
                  + fabsf(wb[j+2]) + fabsf(wb[j+3]);
        }
        // group of 64 elems = this lane quad (i0 = lane*16)
        asum += __shfl_xor(asum, 1, 64);
        asum += __shfl_xor(asum, 2, 64);
        float scale = bf16_rne(asum * (1.0f / 64.0f));
        scale = fmaxf(scale, 1e-8f);
        float inv = 1.0f / scale;
#pragma unroll
        for (int j = 0; j < 16; ++j) {
            float t = rintf(bf16_rne(wb[j] * inv));   // jnp.round = half-even
            t = fminf(fmaxf(t, -1.f), 1.f);
            q[r][j] = t * scale;                      // exact in bf16 set
        }
    }

    float acc[64];
#pragma unroll
    for (int i = 0; i < 64; ++i) acc[i] = 0.f;
#pragma unroll
    for (int k = 0; k < NF; ++k) {
        const float* frow = feat + k * INF + i0;
#pragma unroll
        for (int j = 0; j < 16; j += 4) {
            float4 f4 = *(const float4*)(frow + j);
#pragma unroll
            for (int r = 0; r < 4; ++r) {
                acc[r*16+k] = fmaf(q[r][j+0], f4.x, acc[r*16+k]);
                acc[r*16+k] = fmaf(q[r][j+1], f4.y, acc[r*16+k]);
                acc[r*16+k] = fmaf(q[r][j+2], f4.z, acc[r*16+k]);
                acc[r*16+k] = fmaf(q[r][j+3], f4.w, acc[r*16+k]);
            }
        }
    }
    xreduce64(acc, lane);
    // lane holds p_f for (r,k) = (lane>>4, lane&15)
    float pf = acc[0];
    float ps = sigmoid5(pf);
    float pa = pf * ps;
    int row = rbase + (lane >> 4);
    int k   = lane & 15;
    unsigned short h0, l0, h1, l1;
    split_bf16(th * pa - al * (1.0f - ps), h0, l0);
    split_bf16(-be * pa, h1, l1);
    Ph[row * 32 + k]      = h0;  Pl[row * 32 + k]      = l0;
    Ph[row * 32 + 16 + k] = h1;  Pl[row * 32 + 16 + k] = l1;
}

// ---------------- prep part B: Xe rows -> bf16 hi/lo ----------------
// Xe[n][k] = x_a[n][k],  Xe[n][16+k] = 1 - x_s[n][k]
__device__ __forceinline__ void do_build_xe(
    int blk,
    const float* __restrict__ x, const float* __restrict__ feat,
    unsigned short* __restrict__ Xh, unsigned short* __restrict__ Xl)
{
    const int lane  = threadIdx.x & 63;
    const int wid   = threadIdx.x >> 6;
    const int rbase = blk * 16 + wid * 4;
    const int i0    = lane * 16;

    float4 xv[4][4];
#pragma unroll
    for (int r = 0; r < 4; ++r) {
        const float* xrow = x + (size_t)(rbase + r) * INF + i0;
#pragma unroll
        for (int j = 0; j < 4; ++j) xv[r][j] = *(const float4*)(xrow + j * 4);
    }

    float acc[64];
#pragma unroll
    for (int i = 0; i < 64; ++i) acc[i] = 0.f;
#pragma unroll
    for (int k = 0; k < NF; ++k) {
        const float* frow = feat + k * INF + i0;
#pragma unroll
        for (int j = 0; j < 4; ++j) {
            float4 f4 = *(const float4*)(frow + j * 4);
#pragma unroll
            for (int r = 0; r < 4; ++r) {
                acc[r*16+k] = fmaf(xv[r][j].x, f4.x, acc[r*16+k]);
                acc[r*16+k] = fmaf(xv[r][j].y, f4.y, acc[r*16+k]);
                acc[r*16+k] = fmaf(xv[r][j].z, f4.z, acc[r*16+k]);
                acc[r*16+k] = fmaf(xv[r][j].w, f4.w, acc[r*16+k]);
            }
        }
    }
    xreduce64(acc, lane);
    float xf = acc[0];
    float xs = sigmoid5(xf);
    int row = rbase + (lane >> 4);
    int k   = lane & 15;
    unsigned short h0, l0, h1, l1;
    split_bf16(xf * xs, h0, l0);
    split_bf16(1.0f - xs, h1, l1);
    Xh[row * 32 + k]      = h0;  Xl[row * 32 + k]      = l0;
    Xh[row * 32 + 16 + k] = h1;  Xl[row * 32 + 16 + k] = l1;
}

// Fused prep: blocks [0,256) build Pe, blocks [256,1280) build Xe.
__global__ __launch_bounds__(256) void prep(
    const float* __restrict__ x, const float* __restrict__ feat,
    const float* __restrict__ proto,
    const float* __restrict__ theta, const float* __restrict__ alpha,
    const float* __restrict__ beta,
    unsigned short* __restrict__ Ph, unsigned short* __restrict__ Pl,
    unsigned short* __restrict__ Xh, unsigned short* __restrict__ Xl)
{
    const int blk = blockIdx.x;
    if (blk < NPROTO / 16) {
        do_build_pe(blk, proto, feat, theta, alpha, beta, Ph, Pl);
    } else {
        do_build_xe(blk - NPROTO / 16, x, feat, Xh, Xl);
    }
}

// ------- main: out = Xe (16384x32) @ Pe^T (4096x32), MFMA hi/lo -------
// ONE WAVE per block (64 thr, 16 KiB LDS): no __syncthreads anywhere —
// the transpose buffer is wave-private, compiler lgkmcnt covers the RAW.
// 10 blocks/CU (LDS-limited) give the scheduler independent waves to
// overlap NT store streams with L2 A-fragment stalls of other waves.
// Wave computes 16n x 256o (16 o-tiles x 4 MFMA), XOR-swizzled LDS
// transpose, then 16 NT dwordx4 stores, each 1 KB contiguous in one row.
// MFMA C layout (m89): col=lane&15 -> n, row=(lane>>4)*4+reg -> o.
__global__ __launch_bounds__(64) void main_mm_mfma(
    const unsigned short* __restrict__ Xh, const unsigned short* __restrict__ Xl,
    const unsigned short* __restrict__ Ph, const unsigned short* __restrict__ Pl,
    float* __restrict__ out)
{
    __shared__ float lds[16][256];      // 16 KiB, wave-private (1 wave/block)
    const int lane  = threadIdx.x & 63;
    const int m     = lane & 15;        // n within tile (C col)
    const int b     = lane >> 4;        // K-group / C row-group
    const int nbase = blockIdx.y * 16;
    const int ob    = blockIdx.x * 256;

    // B fragment (Xe): col = n, loaded once per wave
    const size_t boff = (size_t)(nbase + m) * 32 + b * 8;
    const short8 Bh = *(const short8*)(Xh + boff);
    const short8 Bl = *(const short8*)(Xl + boff);

    // col-XOR swizzle: logical col c of row r stored at c ^ (4*(r&7))
    const int wsw = 4 * (m & 7);
    float* myrow = &lds[m][0];
#pragma unroll
    for (int t = 0; t < 16; ++t) {
        const size_t aoff = (size_t)(ob + t * 16 + m) * 32 + b * 8;
        const short8 Ah = *(const short8*)(Ph + aoff);
        const short8 Al = *(const short8*)(Pl + aoff);
        f32x4 acc = {0.f, 0.f, 0.f, 0.f};
        acc = __builtin_amdgcn_mfma_f32_16x16x32_bf16(Ah, Bh, acc, 0, 0, 0);
        acc = __builtin_amdgcn_mfma_f32_16x16x32_bf16(Ah, Bl, acc, 0, 0, 0);
        acc = __builtin_amdgcn_mfma_f32_16x16x32_bf16(Al, Bh, acc, 0, 0, 0);
        acc = __builtin_amdgcn_mfma_f32_16x16x32_bf16(Al, Bl, acc, 0, 0, 0);
        *(f32x4*)(myrow + ((t * 16 + b * 4) ^ wsw)) = acc;  // 4-aligned XOR
    }

    const float* src = &lds[0][0];
#pragma unroll
    for (int r = 0; r < 16; ++r) {
        f32x4 v = *(const f32x4*)(src + r * 256 + ((lane * 4) ^ (4 * (r & 7))));
        f32x4* dst = (f32x4*)(out + (size_t)(nbase + r) * NPROTO + ob + lane * 4);
        __builtin_nontemporal_store(v, dst);
    }
}

extern "C" void kernel_launch(void* const* d_in, const int* in_sizes, int n_in,
                              void* d_out, int out_size, void* d_ws, size_t ws_size,
                              hipStream_t stream) {
    const float* x     = (const float*)d_in[0];
    const float* feat  = (const float*)d_in[1];
    const float* proto = (const float*)d_in[2];
    const float* theta = (const float*)d_in[3];
    const float* alpha = (const float*)d_in[4];
    const float* beta  = (const float*)d_in[5];
    float* out = (float*)d_out;

    unsigned short* Ph = (unsigned short*)d_ws;          // 256 KiB
    unsigned short* Pl = Ph + (size_t)NPROTO * 32;       // 256 KiB
    unsigned short* Xh = Pl + (size_t)NPROTO * 32;       // 1 MiB
    unsigned short* Xl = Xh + (size_t)NROWS * 32;        // 1 MiB

    prep<<<dim3(NPROTO / 16 + NROWS / 16), 256, 0, stream>>>(
        x, feat, proto, theta, alpha, beta, Ph, Pl, Xh, Xl);
    main_mm_mfma<<<dim3(NPROTO / 256, NROWS / 16), 64, 0, stream>>>(Xh, Xl, Ph, Pl, out);
}